// Round 1
// baseline (503.175 us; speedup 1.0000x reference)
//
#include <hip/hip_runtime.h>
#include <stdint.h>

#define EPSF 1e-20f

// ---------------------------------------------------------------------------
// Pass 1: binarize fp32 -> packed sign bits (bit=1 means negative).
// Each wave handles 256 consecutive floats (float4/lane) -> 4 uint64 words.
// Bit order within a 256-chunk is permuted (word c, bit l = element 4l+c),
// but the SAME permutation applies to x and w (row length 4096 % 256 == 0),
// so XOR+popcount over matching word indices is invariant.
// ---------------------------------------------------------------------------
__global__ __launch_bounds__(256)
void binarize_kernel(const float* __restrict__ src,
                     unsigned long long* __restrict__ dst, int n256) {
    int wave = blockIdx.x * 4 + (threadIdx.x >> 6);
    if (wave >= n256) return;
    int lane = threadIdx.x & 63;
    const float4* p = (const float4*)(src + (size_t)wave * 256);
    float4 v = p[lane];
    unsigned long long m0 = __ballot(v.x < -EPSF);
    unsigned long long m1 = __ballot(v.y < -EPSF);
    unsigned long long m2 = __ballot(v.z < -EPSF);
    unsigned long long m3 = __ballot(v.w < -EPSF);
    if (lane < 4) {
        unsigned long long m = (lane == 0) ? m0 : (lane == 1) ? m1
                             : (lane == 2) ? m2 : m3;
        dst[(size_t)wave * 4 + lane] = m;
    }
}

// ---------------------------------------------------------------------------
// Pass 2: binary GEMM via XOR + popcount.
// out[i][j] = 4096 - 2 * popc(xbits_row_i ^ wbits_row_j)
// Block tile 128x128, 256 threads (16x16), 8x8 outputs/thread with
// interleaved rows (tid + 16*r) so LDS reads avoid >2-way bank conflicts
// with the 9-uint4 padded stride.
// ---------------------------------------------------------------------------
#define BM 128
#define BN 128
#define CHUNK_Q 8     // uint4 per row per K-chunk (1024 bits)
#define NCHUNK 4      // 4096 bits total
#define LDSS 9        // LDS row stride in uint4 (pad: +1 over 8)

__global__ __launch_bounds__(256, 2)
void bingemm_kernel(const uint4* __restrict__ xb, const uint4* __restrict__ wb,
                    float* __restrict__ out) {
    __shared__ uint4 xs[BM * LDSS];
    __shared__ uint4 ws[BN * LDSS];

    const int t  = threadIdx.x;
    const int tx = t & 15;
    const int ty = t >> 4;
    const int row0 = blockIdx.y * BM;  // M tile base (x rows)
    const int col0 = blockIdx.x * BN;  // N tile base (w rows)

    int acc[8][8];
#pragma unroll
    for (int a = 0; a < 8; ++a)
#pragma unroll
        for (int b = 0; b < 8; ++b) acc[a][b] = 0;

    // staging: thread t loads quad (t&7) of rows (t>>3) + 32k, k=0..3
    const int srow = t >> 3;  // 0..31
    const int sq   = t & 7;   // 0..7

    for (int c = 0; c < NCHUNK; ++c) {
        __syncthreads();
#pragma unroll
        for (int k = 0; k < 4; ++k) {
            int r = srow + 32 * k;
            xs[r * LDSS + sq] = xb[(size_t)(row0 + r) * 32 + c * CHUNK_Q + sq];
            ws[r * LDSS + sq] = wb[(size_t)(col0 + r) * 32 + c * CHUNK_Q + sq];
        }
        __syncthreads();

#pragma unroll
        for (int q = 0; q < CHUNK_Q; ++q) {
            uint4 xq[8], wq[8];
#pragma unroll
            for (int ri = 0; ri < 8; ++ri)
                xq[ri] = xs[(ty + 16 * ri) * LDSS + q];
#pragma unroll
            for (int cj = 0; cj < 8; ++cj)
                wq[cj] = ws[(tx + 16 * cj) * LDSS + q];
#pragma unroll
            for (int ri = 0; ri < 8; ++ri)
#pragma unroll
                for (int cj = 0; cj < 8; ++cj) {
                    acc[ri][cj] += __builtin_popcount(xq[ri].x ^ wq[cj].x);
                    acc[ri][cj] += __builtin_popcount(xq[ri].y ^ wq[cj].y);
                    acc[ri][cj] += __builtin_popcount(xq[ri].z ^ wq[cj].z);
                    acc[ri][cj] += __builtin_popcount(xq[ri].w ^ wq[cj].w);
                }
        }
    }

#pragma unroll
    for (int ri = 0; ri < 8; ++ri) {
        size_t i = row0 + ty + 16 * ri;
#pragma unroll
        for (int cj = 0; cj < 8; ++cj) {
            int j = col0 + tx + 16 * cj;
            out[i * 4096 + j] = (float)(4096 - 2 * acc[ri][cj]);
        }
    }
}

extern "C" void kernel_launch(void* const* d_in, const int* in_sizes, int n_in,
                              void* d_out, int out_size, void* d_ws, size_t ws_size,
                              hipStream_t stream) {
    const float* x = (const float*)d_in[0];   // [8192, 4096] fp32
    const float* w = (const float*)d_in[1];   // [4096, 4096] fp32
    float* out = (float*)d_out;               // [8192, 4096] fp32

    const int M = 8192, N = 4096, K = 4096;

    // workspace: xbits (M*128 u32 = 4.19MB) then wbits (N*128 u32 = 2.10MB)
    uint32_t* xbits = (uint32_t*)d_ws;
    uint32_t* wbits = xbits + (size_t)M * (K / 32);

    // binarize x: M*K/256 chunks, 4 chunks per 256-thread block
    binarize_kernel<<<(M * K) / 1024, 256, 0, stream>>>(
        x, (unsigned long long*)xbits, (M * K) / 256);
    binarize_kernel<<<(N * K) / 1024, 256, 0, stream>>>(
        w, (unsigned long long*)wbits, (N * K) / 256);

    dim3 grid(N / BN, M / BM);  // (32, 64)
    bingemm_kernel<<<grid, 256, 0, stream>>>(
        (const uint4*)xbits, (const uint4*)wbits, out);
}

// Round 2
// 389.822 us; speedup vs baseline: 1.2908x; 1.2908x over previous
//
#include <hip/hip_runtime.h>
#include <stdint.h>

#define EPSF 1e-20f

typedef __attribute__((ext_vector_type(4))) int i32x4;
typedef __attribute__((ext_vector_type(16))) int i32x16;

// ===========================================================================
// PATH A (primary): binarize to ±1 int8 + MFMA i8 GEMM
// ===========================================================================

// fp32 -> ±1 i8 (0x01 / 0xFF). Thread handles 4 float4 groups (ILP=4),
// strided so both loads and stores are per-instruction coalesced.
__global__ __launch_bounds__(256)
void bin_i8_kernel(const float4* __restrict__ src, uint32_t* __restrict__ dst,
                   int n4) {
    int base = blockIdx.x * 1024 + threadIdx.x;
#pragma unroll
    for (int j = 0; j < 4; ++j) {
        int idx = base + j * 256;
        if (idx < n4) {
            float4 v = src[idx];
            uint32_t b0 = (v.x < -EPSF) ? 0xFFu : 0x01u;
            uint32_t b1 = (v.y < -EPSF) ? 0xFFu : 0x01u;
            uint32_t b2 = (v.z < -EPSF) ? 0xFFu : 0x01u;
            uint32_t b3 = (v.w < -EPSF) ? 0xFFu : 0x01u;
            dst[idx] = b0 | (b1 << 8) | (b2 << 16) | (b3 << 24);
        }
    }
}

// C = Xi8 * Wi8^T via v_mfma_i32_32x32x32_i8.
// 128x128 tile, 256 threads (4 waves, 2x2 of 64x64 per wave, each wave 2x2
// tiles of 32x32). BK = 128 bytes. global_load_lds staging (16B/lane) with
// XOR chunk swizzle (chunk q of row r lives at slot q^(r&7)) so that:
//   - staging keeps the wave-uniform-base + lane*16 contiguity (swizzle is
//     applied to the SOURCE address; each 8-lane row group still covers one
//     contiguous 128B global segment -> coalescing preserved)
//   - compute-side ds_read_b128 is bank-conflict-free (8 bank-groups x
//     2-way, == the 8-cycle floor for a 1KB wave read)
#define GM 128
#define GN 128
#define GK 128

__global__ __launch_bounds__(256, 3)
void i8mfma_gemm(const char* __restrict__ xi8, const char* __restrict__ wi8,
                 float* __restrict__ out) {
    __shared__ char xs[GM * GK];
    __shared__ char wsh[GN * GK];

    const int t = threadIdx.x;
    const int lane = t & 63;
    const int wave = t >> 6;
    const int wm = (wave >> 1) * 64;
    const int wn = (wave & 1) * 64;
    const int row0 = blockIdx.y * GM;
    const int col0 = blockIdx.x * GN;
    const int lrow = lane & 31;
    const int half = lane >> 5;

    i32x16 acc[2][2];
#pragma unroll
    for (int r = 0; r < 2; ++r)
#pragma unroll
        for (int c = 0; c < 2; ++c)
#pragma unroll
            for (int e = 0; e < 16; ++e) acc[r][c][e] = 0;

    for (int kc = 0; kc < 4096; kc += GK) {
        __syncthreads();
#pragma unroll
        for (int j = 0; j < 4; ++j) {
            int c = j * 256 + t;          // 16B chunk id, 0..1023
            int row = c >> 3;             // 0..127
            int q = c & 7;                // LDS slot chunk
            int qg = q ^ (row & 7);       // global chunk feeding this slot
            const char* srcx = xi8 + (size_t)(row0 + row) * 4096 + kc + qg * 16;
            __builtin_amdgcn_global_load_lds((const uint32_t*)srcx,
                                             (uint32_t*)(xs + c * 16), 16, 0, 0);
            const char* srcw = wi8 + (size_t)(col0 + row) * 4096 + kc + qg * 16;
            __builtin_amdgcn_global_load_lds((const uint32_t*)srcw,
                                             (uint32_t*)(wsh + c * 16), 16, 0, 0);
        }
        __syncthreads();

#pragma unroll
        for (int s = 0; s < 4; ++s) {
            int g = 2 * s + half;         // global k-chunk this lane-half needs
            i32x4 a[2], b[2];
#pragma unroll
            for (int r = 0; r < 2; ++r) {
                int row = wm + r * 32 + lrow;
                int qs = g ^ (row & 7);
                a[r] = *(const i32x4*)(xs + row * GK + qs * 16);
            }
#pragma unroll
            for (int c = 0; c < 2; ++c) {
                int col = wn + c * 32 + lrow;
                int qs = g ^ (col & 7);
                b[c] = *(const i32x4*)(wsh + col * GK + qs * 16);
            }
#pragma unroll
            for (int r = 0; r < 2; ++r)
#pragma unroll
                for (int c = 0; c < 2; ++c)
                    acc[r][c] = __builtin_amdgcn_mfma_i32_32x32x32_i8(
                        a[r], b[c], acc[r][c], 0, 0, 0);
        }
    }

    // C/D layout (32x32, dtype-independent, m74/m101/m121-128):
    // col = lane&31, row = (reg&3) + 8*(reg>>2) + 4*(lane>>5)
#pragma unroll
    for (int r = 0; r < 2; ++r)
#pragma unroll
        for (int c = 0; c < 2; ++c)
#pragma unroll
            for (int e = 0; e < 16; ++e) {
                int rr = row0 + wm + r * 32 + (e & 3) + 8 * (e >> 2) + 4 * half;
                int cc = col0 + wn + c * 32 + lrow;
                out[(size_t)rr * 4096 + cc] = (float)acc[r][c][e];
            }
}

// ===========================================================================
// PATH B (fallback if ws_size too small): R1 bit-pack + XOR/popcount GEMM
// (verified correct, 503 us) — kept verbatim for safety.
// ===========================================================================

__global__ __launch_bounds__(256)
void binarize_kernel(const float* __restrict__ src,
                     unsigned long long* __restrict__ dst, int n256) {
    int wave = blockIdx.x * 4 + (threadIdx.x >> 6);
    if (wave >= n256) return;
    int lane = threadIdx.x & 63;
    const float4* p = (const float4*)(src + (size_t)wave * 256);
    float4 v = p[lane];
    unsigned long long m0 = __ballot(v.x < -EPSF);
    unsigned long long m1 = __ballot(v.y < -EPSF);
    unsigned long long m2 = __ballot(v.z < -EPSF);
    unsigned long long m3 = __ballot(v.w < -EPSF);
    if (lane < 4) {
        unsigned long long m = (lane == 0) ? m0 : (lane == 1) ? m1
                             : (lane == 2) ? m2 : m3;
        dst[(size_t)wave * 4 + lane] = m;
    }
}

#define BM 128
#define BN 128
#define CHUNK_Q 8
#define NCHUNK 4
#define LDSS 9

__global__ __launch_bounds__(256, 2)
void bingemm_kernel(const uint4* __restrict__ xb, const uint4* __restrict__ wb,
                    float* __restrict__ out) {
    __shared__ uint4 xsl[BM * LDSS];
    __shared__ uint4 wsl[BN * LDSS];

    const int t  = threadIdx.x;
    const int tx = t & 15;
    const int ty = t >> 4;
    const int row0 = blockIdx.y * BM;
    const int col0 = blockIdx.x * BN;

    int acc[8][8];
#pragma unroll
    for (int a = 0; a < 8; ++a)
#pragma unroll
        for (int b = 0; b < 8; ++b) acc[a][b] = 0;

    const int srow = t >> 3;
    const int sq   = t & 7;

    for (int c = 0; c < NCHUNK; ++c) {
        __syncthreads();
#pragma unroll
        for (int k = 0; k < 4; ++k) {
            int r = srow + 32 * k;
            xsl[r * LDSS + sq] = xb[(size_t)(row0 + r) * 32 + c * CHUNK_Q + sq];
            wsl[r * LDSS + sq] = wb[(size_t)(col0 + r) * 32 + c * CHUNK_Q + sq];
        }
        __syncthreads();

#pragma unroll
        for (int q = 0; q < CHUNK_Q; ++q) {
            uint4 xq[8], wq[8];
#pragma unroll
            for (int ri = 0; ri < 8; ++ri)
                xq[ri] = xsl[(ty + 16 * ri) * LDSS + q];
#pragma unroll
            for (int cj = 0; cj < 8; ++cj)
                wq[cj] = wsl[(tx + 16 * cj) * LDSS + q];
#pragma unroll
            for (int ri = 0; ri < 8; ++ri)
#pragma unroll
                for (int cj = 0; cj < 8; ++cj) {
                    acc[ri][cj] += __builtin_popcount(xq[ri].x ^ wq[cj].x);
                    acc[ri][cj] += __builtin_popcount(xq[ri].y ^ wq[cj].y);
                    acc[ri][cj] += __builtin_popcount(xq[ri].z ^ wq[cj].z);
                    acc[ri][cj] += __builtin_popcount(xq[ri].w ^ wq[cj].w);
                }
        }
    }

#pragma unroll
    for (int ri = 0; ri < 8; ++ri) {
        size_t i = row0 + ty + 16 * ri;
#pragma unroll
        for (int cj = 0; cj < 8; ++cj) {
            int j = col0 + tx + 16 * cj;
            out[i * 4096 + j] = (float)(4096 - 2 * acc[ri][cj]);
        }
    }
}

// ===========================================================================
extern "C" void kernel_launch(void* const* d_in, const int* in_sizes, int n_in,
                              void* d_out, int out_size, void* d_ws, size_t ws_size,
                              hipStream_t stream) {
    const float* x = (const float*)d_in[0];   // [8192, 4096] fp32
    const float* w = (const float*)d_in[1];   // [4096, 4096] fp32
    float* out = (float*)d_out;

    const int M = 8192, N = 4096, K = 4096;
    const size_t need_i8 = (size_t)M * K + (size_t)N * K;  // 50.3 MB

    if (ws_size >= need_i8) {
        char* xi8 = (char*)d_ws;
        char* wi8 = xi8 + (size_t)M * K;

        int n4x = (M * K) / 4;   // 8388608 -> 8192 blocks
        int n4w = (N * K) / 4;   // 4194304 -> 4096 blocks
        bin_i8_kernel<<<n4x / 1024, 256, 0, stream>>>(
            (const float4*)x, (uint32_t*)xi8, n4x);
        bin_i8_kernel<<<n4w / 1024, 256, 0, stream>>>(
            (const float4*)w, (uint32_t*)wi8, n4w);

        dim3 grid(N / GN, M / GM);  // (32, 64)
        i8mfma_gemm<<<grid, 256, 0, stream>>>(xi8, wi8, out);
    } else {
        uint32_t* xbits = (uint32_t*)d_ws;
        uint32_t* wbits = xbits + (size_t)M * (K / 32);

        binarize_kernel<<<(M * K) / 1024, 256, 0, stream>>>(
            x, (unsigned long long*)xbits, (M * K) / 256);
        binarize_kernel<<<(N * K) / 1024, 256, 0, stream>>>(
            w, (unsigned long long*)wbits, (N * K) / 256);

        dim3 grid(N / BN, M / BM);
        bingemm_kernel<<<grid, 256, 0, stream>>>(
            (const uint4*)xbits, (const uint4*)wbits, out);
    }
}